// Round 1
// baseline (2262.079 us; speedup 1.0000x reference)
//
#include <hip/hip_runtime.h>
#include <hip/hip_bf16.h>
#include <math.h>

#define N_NODES 100000
#define N_EDGES 1600000
#define D 64
#define H 128
#define LN_EPS 1e-5f

// ---------------------------------------------------------------------------
// Kernel 1: zero the aggregation buffer (d_ws is poisoned 0xAA every call)
// ---------------------------------------------------------------------------
__global__ void zero_agg(float* __restrict__ agg) {
    const long long total = (long long)N_NODES * D / 4;   // float4 count
    long long i = (long long)blockIdx.x * blockDim.x + threadIdx.x;
    const long long stride = (long long)gridDim.x * blockDim.x;
    float4 z = make_float4(0.f, 0.f, 0.f, 0.f);
    for (; i < total; i += stride)
        ((float4*)agg)[i] = z;
}

// ---------------------------------------------------------------------------
// Kernel 2: copy efeat -> out (first tuple element) and scatter-add into agg.
// One float4 chunk per thread; 16 chunks per edge row (D=64).
// ---------------------------------------------------------------------------
__global__ void scatter_copy(const float* __restrict__ efeat,
                             const int* __restrict__ dst,
                             float* __restrict__ out_e,
                             float* __restrict__ agg) {
    const long long total = (long long)N_EDGES * (D / 4);  // 25.6M chunks
    long long t = (long long)blockIdx.x * blockDim.x + threadIdx.x;
    const long long stride = (long long)gridDim.x * blockDim.x;
    for (; t < total; t += stride) {
        long long e = t >> 4;          // edge index
        int c = (int)(t & 15);         // chunk within row
        float4 v = ((const float4*)efeat)[t];
        ((float4*)out_e)[t] = v;       // pass-through output
        int base = dst[e] * D + c * 4;
        unsafeAtomicAdd(&agg[base + 0], v.x);
        unsafeAtomicAdd(&agg[base + 1], v.y);
        unsafeAtomicAdd(&agg[base + 2], v.z);
        unsafeAtomicAdd(&agg[base + 3], v.w);
    }
}

// ---------------------------------------------------------------------------
// Kernel 3: fused  concat -> Linear(128x128) -> SiLU -> Linear(128x64)
//                 -> LayerNorm -> +nfeat
// One wave processes NB=4 nodes per iteration. lane d (0..63) owns output
// dim d (and hidden dims 2d, 2d+1). Weights staged in LDS (~97 KB -> 1
// block/CU, 16 waves). Cross-lane broadcasts via __shfl (wave=64).
// ---------------------------------------------------------------------------
#define MLP_BLOCK 1024
#define MLP_WAVES (MLP_BLOCK / 64)
#define NB 4

__global__ __launch_bounds__(MLP_BLOCK, 1)
void mlp_ln(const float* __restrict__ agg,
            const float* __restrict__ nfeat,
            const float* __restrict__ W1, const float* __restrict__ b1,
            const float* __restrict__ W2, const float* __restrict__ b2,
            const float* __restrict__ gamma, const float* __restrict__ beta,
            float* __restrict__ out_n) {
    __shared__ float W1s[H * H];   // 64 KB, row-major [k][j]
    __shared__ float W2s[H * D];   // 32 KB, row-major [k][d]
    __shared__ float b1s[H];
    __shared__ float b2s[D], gs[D], bs[D];

    const int tid = threadIdx.x;
    for (int i = tid; i < H * H / 4; i += MLP_BLOCK)
        ((float4*)W1s)[i] = ((const float4*)W1)[i];
    for (int i = tid; i < H * D / 4; i += MLP_BLOCK)
        ((float4*)W2s)[i] = ((const float4*)W2)[i];
    if (tid < H) b1s[tid] = b1[tid];
    if (tid < D) { b2s[tid] = b2[tid]; gs[tid] = gamma[tid]; bs[tid] = beta[tid]; }
    __syncthreads();

    const int lane = tid & 63;
    const int wave = tid >> 6;
    const int gw = blockIdx.x * MLP_WAVES + wave;
    const int nWaves = gridDim.x * MLP_WAVES;
    const int G = N_NODES / NB;    // 25000 groups (N divisible by NB)

    const float2 bb = ((const float2*)b1s)[lane];
    const float b2v = b2s[lane];
    const float gv = gs[lane], bv = bs[lane];

    for (int g = gw; g < G; g += nWaves) {
        const int n0 = g * NB;
        float a[NB], nf[NB];
        #pragma unroll
        for (int nb = 0; nb < NB; ++nb) {
            a[nb]  = agg  [(long long)(n0 + nb) * D + lane];
            nf[nb] = nfeat[(long long)(n0 + nb) * D + lane];
        }

        // ---- GEMM1: h[j] = b1[j] + sum_k cat[k] * W1[k][j], j = 2*lane, 2*lane+1
        float h0[NB], h1[NB];
        #pragma unroll
        for (int nb = 0; nb < NB; ++nb) { h0[nb] = bb.x; h1[nb] = bb.y; }
        #pragma unroll 8
        for (int k = 0; k < 64; ++k) {          // cat[k] = agg[n][k]
            float2 w = ((const float2*)W1s)[k * 64 + lane];
            #pragma unroll
            for (int nb = 0; nb < NB; ++nb) {
                float c = __shfl(a[nb], k);
                h0[nb] += c * w.x;
                h1[nb] += c * w.y;
            }
        }
        #pragma unroll 8
        for (int k = 0; k < 64; ++k) {          // cat[64+k] = nfeat[n][k]
            float2 w = ((const float2*)W1s)[(k + 64) * 64 + lane];
            #pragma unroll
            for (int nb = 0; nb < NB; ++nb) {
                float c = __shfl(nf[nb], k);
                h0[nb] += c * w.x;
                h1[nb] += c * w.y;
            }
        }

        // ---- SiLU
        float s0[NB], s1[NB];
        #pragma unroll
        for (int nb = 0; nb < NB; ++nb) {
            s0[nb] = h0[nb] / (1.f + __expf(-h0[nb]));
            s1[nb] = h1[nb] / (1.f + __expf(-h1[nb]));
        }

        // ---- GEMM2: h2[d] = b2[d] + sum_k sh[k] * W2[k][d], d = lane
        //      sh[2k'] lives in s0 (lane k'), sh[2k'+1] in s1 (lane k')
        float v[NB];
        #pragma unroll
        for (int nb = 0; nb < NB; ++nb) v[nb] = b2v;
        #pragma unroll 8
        for (int k = 0; k < 64; ++k) {
            float w0 = W2s[(2 * k)     * D + lane];
            float w1 = W2s[(2 * k + 1) * D + lane];
            #pragma unroll
            for (int nb = 0; nb < NB; ++nb) {
                v[nb] += __shfl(s0[nb], k) * w0;
                v[nb] += __shfl(s1[nb], k) * w1;
            }
        }

        // ---- LayerNorm over the 64 lanes + residual
        #pragma unroll
        for (int nb = 0; nb < NB; ++nb) {
            float x = v[nb];
            float sum = x, sq = x * x;
            #pragma unroll
            for (int off = 32; off > 0; off >>= 1) {
                sum += __shfl_xor(sum, off);
                sq  += __shfl_xor(sq,  off);
            }
            float mu  = sum * (1.f / 64.f);
            float var = sq * (1.f / 64.f) - mu * mu;
            float rs  = rsqrtf(var + LN_EPS);
            out_n[(long long)(n0 + nb) * D + lane] = (x - mu) * rs * gv + bv + nf[nb];
        }
    }
}

// ---------------------------------------------------------------------------
extern "C" void kernel_launch(void* const* d_in, const int* in_sizes, int n_in,
                              void* d_out, int out_size, void* d_ws, size_t ws_size,
                              hipStream_t stream) {
    const float* efeat = (const float*)d_in[0];
    const float* nfeat = (const float*)d_in[1];
    const int*   dst   = (const int*)  d_in[2];
    const float* W1    = (const float*)d_in[3];
    const float* b1    = (const float*)d_in[4];
    const float* W2    = (const float*)d_in[5];
    const float* b2    = (const float*)d_in[6];
    const float* gamma = (const float*)d_in[7];
    const float* beta  = (const float*)d_in[8];

    float* out_e = (float*)d_out;                              // [E, D] pass-through
    float* out_n = (float*)d_out + (long long)N_EDGES * D;     // [N, D] new nfeat
    float* agg   = (float*)d_ws;                               // [N, D] accumulator

    zero_agg<<<2048, 256, 0, stream>>>(agg);
    scatter_copy<<<2048, 256, 0, stream>>>(efeat, dst, out_e, agg);
    mlp_ln<<<256, MLP_BLOCK, 0, stream>>>(agg, nfeat, W1, b1, W2, b2,
                                          gamma, beta, out_n);
}

// Round 2
// 1138.804 us; speedup vs baseline: 1.9864x; 1.9864x over previous
//
#include <hip/hip_runtime.h>
#include <hip/hip_bf16.h>
#include <math.h>

#define N_NODES 100000
#define N_EDGES 1600000
#define D 64
#define H 128
#define LN_EPS 1e-5f

// ---------------------------------------------------------------------------
// ws layout (ints):
//   eidx    [N_EDGES]    edge ids binned by dst node (CSR adjacency)
//   cnt     [N_NODES]    per-node degree
//   starts  [N_NODES]    CSR row starts (exclusive scan of cnt)
//   cursor  [N_NODES]    scatter cursors for binning
//   chunkSum[128], chunkOff[128]   scan temporaries (chunk = 1024 elements)
// total ~7.6 MB  (previous round used 25.6 MB of ws successfully)
// ---------------------------------------------------------------------------
#define NCHUNK ((N_NODES + 1023) / 1024)   // 98

// ---- zero the histogram (ws is poisoned 0xAA before every call) -----------
__global__ void zero_cnt(int* __restrict__ cnt) {
    int i = blockIdx.x * blockDim.x + threadIdx.x;
    if (i < N_NODES) cnt[i] = 0;
}

// ---- pass-through copy of efeat + degree histogram ------------------------
__global__ void copy_hist(const float4* __restrict__ ef4,
                          float4* __restrict__ out4,
                          const int* __restrict__ dst,
                          int* __restrict__ cnt) {
    const int total4 = N_EDGES * (D / 4);            // 25.6M float4
    const int stride = gridDim.x * blockDim.x;
    for (int i = blockIdx.x * blockDim.x + threadIdx.x; i < total4; i += stride)
        out4[i] = ef4[i];
    for (int e = blockIdx.x * blockDim.x + threadIdx.x; e < N_EDGES; e += stride)
        atomicAdd(&cnt[dst[e]], 1);
}

// ---- scan step 1: per-1024-chunk exclusive scan + chunk totals ------------
__global__ void scan1(const int* __restrict__ cnt,
                      int* __restrict__ starts,
                      int* __restrict__ chunkSum) {
    __shared__ int ps[256];
    const int t = threadIdx.x;
    const int base = blockIdx.x * 1024 + t * 4;
    int v[4];
    #pragma unroll
    for (int r = 0; r < 4; ++r)
        v[r] = (base + r < N_NODES) ? cnt[base + r] : 0;
    int s = v[0] + v[1] + v[2] + v[3];
    ps[t] = s;
    __syncthreads();
    for (int off = 1; off < 256; off <<= 1) {
        int x = (t >= off) ? ps[t - off] : 0;
        __syncthreads();
        ps[t] += x;
        __syncthreads();
    }
    int excl = (t > 0) ? ps[t - 1] : 0;              // exclusive over threads
    int run = excl;
    #pragma unroll
    for (int r = 0; r < 4; ++r) {
        if (base + r < N_NODES) starts[base + r] = run;
        run += v[r];
    }
    if (t == 255) chunkSum[blockIdx.x] = ps[255];
}

// ---- scan step 2: single block scans the 98 chunk totals ------------------
__global__ void scan2(const int* __restrict__ chunkSum,
                      int* __restrict__ chunkOff) {
    __shared__ int ps[128];
    const int t = threadIdx.x;                        // block of 128
    int own = (t < NCHUNK) ? chunkSum[t] : 0;
    ps[t] = own;
    __syncthreads();
    for (int off = 1; off < 128; off <<= 1) {
        int x = (t >= off) ? ps[t - off] : 0;
        __syncthreads();
        ps[t] += x;
        __syncthreads();
    }
    chunkOff[t] = ps[t] - own;                        // exclusive
}

// ---- scan step 3: add chunk offsets, init cursors -------------------------
__global__ void scan3(int* __restrict__ starts,
                      const int* __restrict__ chunkOff,
                      int* __restrict__ cursor) {
    const int stride = gridDim.x * blockDim.x;
    for (int i = blockIdx.x * blockDim.x + threadIdx.x; i < N_NODES; i += stride) {
        int s = starts[i] + chunkOff[i >> 10];
        starts[i] = s;
        cursor[i] = s;
    }
}

// ---- bin edge ids into CSR adjacency --------------------------------------
__global__ void bin_edges(const int* __restrict__ dst,
                          int* __restrict__ cursor,
                          int* __restrict__ eidx) {
    const int stride = gridDim.x * blockDim.x;
    for (int e = blockIdx.x * blockDim.x + threadIdx.x; e < N_EDGES; e += stride) {
        int pos = atomicAdd(&cursor[dst[e]], 1);
        eidx[pos] = e;
    }
}

// ---------------------------------------------------------------------------
// Fused: CSR gather-sum -> concat -> Linear(128,128) -> SiLU -> Linear(128,64)
//        -> LayerNorm -> + nfeat
// Block = 512 threads (8 waves), tile = 128 nodes.
// LDS XT[128][132] (67.6 KB, stride 132 => 16B-aligned rows, 2-way banks):
//   phase A: XT[k][n] transposed activations (k<64 agg, k>=64 nfeat)
//   phase B: sT[h][n] silu(hidden) transposed
//   phase C: O[n][d]  pre-LN output, flat stride 66
// Thread tile: nodes {nt*4+i, 64+nt*4+i} x 4 hidden (GEMM1) / 2 dims (GEMM2)
// ---------------------------------------------------------------------------
__device__ __forceinline__ float silu_f(float x) {
    return x / (1.f + __expf(-x));
}

__global__ __launch_bounds__(512, 4)
void fused_mlp(const float* __restrict__ efeat, const float* __restrict__ nfeat,
               const int* __restrict__ starts, const int* __restrict__ cnt,
               const int* __restrict__ eidx,
               const float* __restrict__ W1, const float* __restrict__ b1,
               const float* __restrict__ W2, const float* __restrict__ b2,
               const float* __restrict__ gamma, const float* __restrict__ beta,
               float* __restrict__ out_n) {
    __shared__ float XT[128][132];

    const int tid  = threadIdx.x;
    const int lane = tid & 63;
    const int wave = tid >> 6;          // 0..7
    const int nbase = blockIdx.x * 128;

    const float gl = gamma[lane];
    const float bl = beta[lane];

    // ---------------- Phase 0: gather agg rows (CSR) + nfeat, transpose ----
    float nf[16];
    #pragma unroll 1
    for (int i = 0; i < 16; ++i) {
        const int col = wave * 16 + i;
        const int n = nbase + col;
        float a = 0.f, nv = 0.f;
        if (n < N_NODES) {
            int st  = __builtin_amdgcn_readfirstlane(starts[n]);
            int deg = __builtin_amdgcn_readfirstlane(cnt[n]);
            // prefetch up to 64 edge ids into lanes, broadcast via shfl
            int eid_l = (lane < deg) ? eidx[st + lane] : 0;
            const int m = deg < 64 ? deg : 64;
            int e = 0;
            for (; e + 8 <= m; e += 8) {
                float v[8];
                #pragma unroll
                for (int j = 0; j < 8; ++j) {
                    int id = __shfl(eid_l, e + j);
                    v[j] = efeat[id * D + lane];
                }
                #pragma unroll
                for (int j = 0; j < 8; ++j) a += v[j];
            }
            for (; e < m; ++e) {
                int id = __shfl(eid_l, e);
                a += efeat[id * D + lane];
            }
            for (; e < deg; ++e)                       // deg > 64 (rare)
                a += efeat[eidx[st + e] * D + lane];
            nv = nfeat[(long long)n * D + lane];
        }
        XT[lane][col]      = a;        // cat dims 0..63   (agg)
        XT[64 + lane][col] = nv;       // cat dims 64..127 (nfeat)
        nf[i] = nv;
    }
    __syncthreads();

    // ---------------- GEMM1: h = cat @ W1 + b1  (K=128, out 128x128) -------
    const int nt = tid & 15;            // node tile: {nt*4+i, 64+nt*4+i}
    const int ht = tid >> 4;            // 0..31, hidden j0 = ht*4
    const int j0 = ht * 4;

    float acc0[4][4], acc1[4][4];
    {
        const float4 b4 = *(const float4*)(b1 + j0);
        const float bj[4] = {b4.x, b4.y, b4.z, b4.w};
        #pragma unroll
        for (int i = 0; i < 4; ++i)
            #pragma unroll
            for (int j = 0; j < 4; ++j) { acc0[i][j] = bj[j]; acc1[i][j] = bj[j]; }
    }
    #pragma unroll 4
    for (int k = 0; k < 2 * D; ++k) {
        const float4 w4 = *(const float4*)(W1 + k * H + j0);
        const float4 xa = *(const float4*)(&XT[k][nt * 4]);
        const float4 xb = *(const float4*)(&XT[k][64 + nt * 4]);
        const float wv[4] = {w4.x, w4.y, w4.z, w4.w};
        const float av[4] = {xa.x, xa.y, xa.z, xa.w};
        const float bv[4] = {xb.x, xb.y, xb.z, xb.w};
        #pragma unroll
        for (int i = 0; i < 4; ++i)
            #pragma unroll
            for (int j = 0; j < 4; ++j) {
                acc0[i][j] = fmaf(av[i], wv[j], acc0[i][j]);
                acc1[i][j] = fmaf(bv[i], wv[j], acc1[i][j]);
            }
    }
    __syncthreads();   // everyone done reading XT

    // ---------------- SiLU + transposed store sT[h][n] ----------------------
    #pragma unroll
    for (int j = 0; j < 4; ++j) {
        *(float4*)(&XT[j0 + j][nt * 4]) =
            make_float4(silu_f(acc0[0][j]), silu_f(acc0[1][j]),
                        silu_f(acc0[2][j]), silu_f(acc0[3][j]));
        *(float4*)(&XT[j0 + j][64 + nt * 4]) =
            make_float4(silu_f(acc1[0][j]), silu_f(acc1[1][j]),
                        silu_f(acc1[2][j]), silu_f(acc1[3][j]));
    }
    __syncthreads();

    // ---------------- GEMM2: o = s @ W2 + b2  (K=128, out 128x64) ----------
    const int dt = tid >> 4;            // 0..31, d0 = dt*2
    const int d0 = dt * 2;
    float o0[4][2], o1[4][2];
    {
        const float2 b2v = *(const float2*)(b2 + d0);
        #pragma unroll
        for (int i = 0; i < 4; ++i) {
            o0[i][0] = b2v.x; o0[i][1] = b2v.y;
            o1[i][0] = b2v.x; o1[i][1] = b2v.y;
        }
    }
    #pragma unroll 4
    for (int h = 0; h < H; ++h) {
        const float2 w2v = *(const float2*)(W2 + h * D + d0);
        const float4 sa = *(const float4*)(&XT[h][nt * 4]);
        const float4 sb = *(const float4*)(&XT[h][64 + nt * 4]);
        const float sav[4] = {sa.x, sa.y, sa.z, sa.w};
        const float sbv[4] = {sb.x, sb.y, sb.z, sb.w};
        #pragma unroll
        for (int i = 0; i < 4; ++i) {
            o0[i][0] = fmaf(sav[i], w2v.x, o0[i][0]);
            o0[i][1] = fmaf(sav[i], w2v.y, o0[i][1]);
            o1[i][0] = fmaf(sbv[i], w2v.x, o1[i][0]);
            o1[i][1] = fmaf(sbv[i], w2v.y, o1[i][1]);
        }
    }
    __syncthreads();   // done reading sT

    // ---------------- store pre-LN output O[n][d], stride 66 ----------------
    float* O = &XT[0][0];
    #pragma unroll
    for (int i = 0; i < 4; ++i) {
        *(float2*)(O + (nt * 4 + i) * 66 + d0)      = make_float2(o0[i][0], o0[i][1]);
        *(float2*)(O + (64 + nt * 4 + i) * 66 + d0) = make_float2(o1[i][0], o1[i][1]);
    }
    __syncthreads();

    // ---------------- LayerNorm + residual, wave handles its 16 nodes ------
    #pragma unroll 1
    for (int i = 0; i < 16; ++i) {
        const int col = wave * 16 + i;
        const int gn = nbase + col;
        float x = O[col * 66 + lane];
        float s = x, q = x * x;
        #pragma unroll
        for (int off = 32; off > 0; off >>= 1) {
            s += __shfl_xor(s, off);
            q += __shfl_xor(q, off);
        }
        const float mu  = s * (1.f / 64.f);
        const float var = q * (1.f / 64.f) - mu * mu;
        const float rs  = rsqrtf(var + LN_EPS);
        if (gn < N_NODES)
            out_n[(long long)gn * D + lane] = (x - mu) * rs * gl + bl + nf[i];
    }
}

// ---------------------------------------------------------------------------
extern "C" void kernel_launch(void* const* d_in, const int* in_sizes, int n_in,
                              void* d_out, int out_size, void* d_ws, size_t ws_size,
                              hipStream_t stream) {
    const float* efeat = (const float*)d_in[0];
    const float* nfeat = (const float*)d_in[1];
    const int*   dst   = (const int*)  d_in[2];
    const float* W1    = (const float*)d_in[3];
    const float* b1    = (const float*)d_in[4];
    const float* W2    = (const float*)d_in[5];
    const float* b2    = (const float*)d_in[6];
    const float* gamma = (const float*)d_in[7];
    const float* beta  = (const float*)d_in[8];

    float* out_e = (float*)d_out;                              // [E, D]
    float* out_n = (float*)d_out + (long long)N_EDGES * D;     // [N, D]

    int* W      = (int*)d_ws;
    int* eidx   = W;
    int* cnt    = eidx + N_EDGES;
    int* starts = cnt + N_NODES;
    int* cursor = starts + N_NODES;
    int* chunkSum = cursor + N_NODES;
    int* chunkOff = chunkSum + 128;

    zero_cnt <<<(N_NODES + 255) / 256, 256, 0, stream>>>(cnt);
    copy_hist<<<2048, 256, 0, stream>>>((const float4*)efeat, (float4*)out_e,
                                        dst, cnt);
    scan1    <<<NCHUNK, 256, 0, stream>>>(cnt, starts, chunkSum);
    scan2    <<<1, 128, 0, stream>>>(chunkSum, chunkOff);
    scan3    <<<512, 256, 0, stream>>>(starts, chunkOff, cursor);
    bin_edges<<<1024, 256, 0, stream>>>(dst, cursor, eidx);
    fused_mlp<<<(N_NODES + 127) / 128, 512, 0, stream>>>(
        efeat, nfeat, starts, cnt, eidx, W1, b1, W2, b2, gamma, beta, out_n);
}

// Round 3
// 1100.414 us; speedup vs baseline: 2.0557x; 1.0349x over previous
//
#include <hip/hip_runtime.h>
#include <hip/hip_bf16.h>
#include <math.h>

#define N_NODES 100000
#define N_EDGES 1600000
#define D 64
#define H 128
#define LN_EPS 1e-5f

// ---------------------------------------------------------------------------
// ws layout (ints): eidx[E], cnt[N], starts[N], cursor[N], chunkSum[128],
// chunkOff[128].  CSR build: hist -> scan -> bin.  Edge rows are then COPIED
// to out_e inside the gather (CSR is a permutation of edges), deleting the
// separate 410 MB copy pass.
// ---------------------------------------------------------------------------
#define NCHUNK ((N_NODES + 1023) / 1024)   // 98

__global__ void zero_cnt(int* __restrict__ cnt) {
    int i = blockIdx.x * blockDim.x + threadIdx.x;
    if (i < N_NODES) cnt[i] = 0;
}

__global__ void hist(const int* __restrict__ dst, int* __restrict__ cnt) {
    const int stride = gridDim.x * blockDim.x;
    for (int e = blockIdx.x * blockDim.x + threadIdx.x; e < N_EDGES; e += stride)
        atomicAdd(&cnt[dst[e]], 1);
}

__global__ void scan1(const int* __restrict__ cnt,
                      int* __restrict__ starts,
                      int* __restrict__ chunkSum) {
    __shared__ int ps[256];
    const int t = threadIdx.x;
    const int base = blockIdx.x * 1024 + t * 4;
    int v[4];
    #pragma unroll
    for (int r = 0; r < 4; ++r)
        v[r] = (base + r < N_NODES) ? cnt[base + r] : 0;
    int s = v[0] + v[1] + v[2] + v[3];
    ps[t] = s;
    __syncthreads();
    for (int off = 1; off < 256; off <<= 1) {
        int x = (t >= off) ? ps[t - off] : 0;
        __syncthreads();
        ps[t] += x;
        __syncthreads();
    }
    int run = (t > 0) ? ps[t - 1] : 0;
    #pragma unroll
    for (int r = 0; r < 4; ++r) {
        if (base + r < N_NODES) starts[base + r] = run;
        run += v[r];
    }
    if (t == 255) chunkSum[blockIdx.x] = ps[255];
}

__global__ void scan2(const int* __restrict__ chunkSum,
                      int* __restrict__ chunkOff) {
    __shared__ int ps[128];
    const int t = threadIdx.x;
    int own = (t < NCHUNK) ? chunkSum[t] : 0;
    ps[t] = own;
    __syncthreads();
    for (int off = 1; off < 128; off <<= 1) {
        int x = (t >= off) ? ps[t - off] : 0;
        __syncthreads();
        ps[t] += x;
        __syncthreads();
    }
    chunkOff[t] = ps[t] - own;
}

__global__ void scan3(int* __restrict__ starts,
                      const int* __restrict__ chunkOff,
                      int* __restrict__ cursor) {
    const int stride = gridDim.x * blockDim.x;
    for (int i = blockIdx.x * blockDim.x + threadIdx.x; i < N_NODES; i += stride) {
        int s = starts[i] + chunkOff[i >> 10];
        starts[i] = s;
        cursor[i] = s;
    }
}

__global__ void bin_edges(const int* __restrict__ dst,
                          int* __restrict__ cursor,
                          int* __restrict__ eidx) {
    const int stride = gridDim.x * blockDim.x;
    for (int e = blockIdx.x * blockDim.x + threadIdx.x; e < N_EDGES; e += stride) {
        int pos = atomicAdd(&cursor[dst[e]], 1);
        eidx[pos] = e;
    }
}

// ---------------------------------------------------------------------------
// Fused: CSR gather-sum (+ efeat pass-through copy) -> concat -> Linear ->
//        SiLU -> Linear -> LayerNorm -> + nfeat
// Block = 512 threads (8 waves), tile = 128 nodes, LDS XT[128][132] (67.6 KB).
// Gather is 4-row-vectorized: rowgroup rg = lane>>4 picks the edge row,
// quad q = lane&15 picks the float4 within the row -> 1 KB per wave-load.
// ---------------------------------------------------------------------------
__device__ __forceinline__ float silu_f(float x) {
    return x / (1.f + __expf(-x));
}

__global__ __launch_bounds__(512, 4)
void fused_mlp(const float4* __restrict__ ef4, float4* __restrict__ out4,
               const float* __restrict__ nfeat,
               const int* __restrict__ starts, const int* __restrict__ cnt,
               const int* __restrict__ eidx,
               const float* __restrict__ W1, const float* __restrict__ b1,
               const float* __restrict__ W2, const float* __restrict__ b2,
               const float* __restrict__ gamma, const float* __restrict__ beta,
               float* __restrict__ out_n) {
    __shared__ float XT[128][132];

    const int tid  = threadIdx.x;
    const int lane = tid & 63;
    const int wave = tid >> 6;
    const int rg   = lane >> 4;        // edge-row group 0..3
    const int q    = lane & 15;        // float4 index within row
    const int nbase = blockIdx.x * 128;

    const float gl = gamma[lane];
    const float bl = beta[lane];

    // ---------------- Phase 0: gather+copy, transpose into XT --------------
    float nf[16];
    #pragma unroll 1
    for (int i = 0; i < 16; ++i) {
        const int col = wave * 16 + i;
        const int n = nbase + col;
        if (n < N_NODES) {
            const int st  = __builtin_amdgcn_readfirstlane(starts[n]);
            const int deg = __builtin_amdgcn_readfirstlane(cnt[n]);
            float4 acc = make_float4(0.f, 0.f, 0.f, 0.f);
            for (int base = 0; base < deg; base += 64) {
                const int m = min(deg - base, 64);
                int eid_l = (lane < m) ? eidx[st + base + lane] : 0;
                for (int c = 0; c < m; c += 4) {
                    const int row = c + rg;
                    const int id = __shfl(eid_l, row);
                    if (row < m) {
                        float4 v = ef4[id * 16 + q];
                        out4[id * 16 + q] = v;          // pass-through copy
                        acc.x += v.x; acc.y += v.y; acc.z += v.z; acc.w += v.w;
                    }
                }
            }
            // reduce the 4 row-groups
            acc.x += __shfl_xor(acc.x, 16); acc.y += __shfl_xor(acc.y, 16);
            acc.z += __shfl_xor(acc.z, 16); acc.w += __shfl_xor(acc.w, 16);
            acc.x += __shfl_xor(acc.x, 32); acc.y += __shfl_xor(acc.y, 32);
            acc.z += __shfl_xor(acc.z, 32); acc.w += __shfl_xor(acc.w, 32);
            if (lane < 16) {
                XT[q * 4 + 0][col] = acc.x;
                XT[q * 4 + 1][col] = acc.y;
                XT[q * 4 + 2][col] = acc.z;
                XT[q * 4 + 3][col] = acc.w;
            }
            const float nv = nfeat[(long long)n * D + lane];
            XT[64 + lane][col] = nv;
            nf[i] = nv;
        } else {
            if (lane < 16) {
                XT[q * 4 + 0][col] = 0.f; XT[q * 4 + 1][col] = 0.f;
                XT[q * 4 + 2][col] = 0.f; XT[q * 4 + 3][col] = 0.f;
            }
            XT[64 + lane][col] = 0.f;
            nf[i] = 0.f;
        }
    }
    __syncthreads();

    // ---------------- GEMM1: h = cat @ W1 + b1 ------------------------------
    const int nt = tid & 15;
    const int j0 = (tid >> 4) * 4;

    float acc0[4][4], acc1[4][4];
    {
        const float4 b4 = *(const float4*)(b1 + j0);
        const float bj[4] = {b4.x, b4.y, b4.z, b4.w};
        #pragma unroll
        for (int i = 0; i < 4; ++i)
            #pragma unroll
            for (int j = 0; j < 4; ++j) { acc0[i][j] = bj[j]; acc1[i][j] = bj[j]; }
    }
    #pragma unroll 4
    for (int k = 0; k < 2 * D; ++k) {
        const float4 w4 = *(const float4*)(W1 + k * H + j0);
        const float4 xa = *(const float4*)(&XT[k][nt * 4]);
        const float4 xb = *(const float4*)(&XT[k][64 + nt * 4]);
        const float wv[4] = {w4.x, w4.y, w4.z, w4.w};
        const float av[4] = {xa.x, xa.y, xa.z, xa.w};
        const float bv[4] = {xb.x, xb.y, xb.z, xb.w};
        #pragma unroll
        for (int i = 0; i < 4; ++i)
            #pragma unroll
            for (int j = 0; j < 4; ++j) {
                acc0[i][j] = fmaf(av[i], wv[j], acc0[i][j]);
                acc1[i][j] = fmaf(bv[i], wv[j], acc1[i][j]);
            }
    }
    __syncthreads();

    // ---------------- SiLU + transposed store sT[h][n] ----------------------
    #pragma unroll
    for (int j = 0; j < 4; ++j) {
        *(float4*)(&XT[j0 + j][nt * 4]) =
            make_float4(silu_f(acc0[0][j]), silu_f(acc0[1][j]),
                        silu_f(acc0[2][j]), silu_f(acc0[3][j]));
        *(float4*)(&XT[j0 + j][64 + nt * 4]) =
            make_float4(silu_f(acc1[0][j]), silu_f(acc1[1][j]),
                        silu_f(acc1[2][j]), silu_f(acc1[3][j]));
    }
    __syncthreads();

    // ---------------- GEMM2: o = s @ W2 + b2 --------------------------------
    const int d0 = (tid >> 4) * 2;
    float o0[4][2], o1[4][2];
    {
        const float2 b2v = *(const float2*)(b2 + d0);
        #pragma unroll
        for (int i = 0; i < 4; ++i) {
            o0[i][0] = b2v.x; o0[i][1] = b2v.y;
            o1[i][0] = b2v.x; o1[i][1] = b2v.y;
        }
    }
    #pragma unroll 4
    for (int h = 0; h < H; ++h) {
        const float2 w2v = *(const float2*)(W2 + h * D + d0);
        const float4 sa = *(const float4*)(&XT[h][nt * 4]);
        const float4 sb = *(const float4*)(&XT[h][64 + nt * 4]);
        const float sav[4] = {sa.x, sa.y, sa.z, sa.w};
        const float sbv[4] = {sb.x, sb.y, sb.z, sb.w};
        #pragma unroll
        for (int i = 0; i < 4; ++i) {
            o0[i][0] = fmaf(sav[i], w2v.x, o0[i][0]);
            o0[i][1] = fmaf(sav[i], w2v.y, o0[i][1]);
            o1[i][0] = fmaf(sbv[i], w2v.x, o1[i][0]);
            o1[i][1] = fmaf(sbv[i], w2v.y, o1[i][1]);
        }
    }
    __syncthreads();

    // ---------------- store pre-LN output O[n][d], stride 66 ----------------
    float* O = &XT[0][0];
    #pragma unroll
    for (int i = 0; i < 4; ++i) {
        *(float2*)(O + (nt * 4 + i) * 66 + d0)      = make_float2(o0[i][0], o0[i][1]);
        *(float2*)(O + (64 + nt * 4 + i) * 66 + d0) = make_float2(o1[i][0], o1[i][1]);
    }
    __syncthreads();

    // ---------------- LayerNorm + residual ----------------------------------
    #pragma unroll 1
    for (int i = 0; i < 16; ++i) {
        const int col = wave * 16 + i;
        const int gn = nbase + col;
        float x = O[col * 66 + lane];
        float s = x, qq = x * x;
        #pragma unroll
        for (int off = 32; off > 0; off >>= 1) {
            s  += __shfl_xor(s,  off);
            qq += __shfl_xor(qq, off);
        }
        const float mu  = s * (1.f / 64.f);
        const float var = qq * (1.f / 64.f) - mu * mu;
        const float rs  = rsqrtf(var + LN_EPS);
        if (gn < N_NODES)
            out_n[(long long)gn * D + lane] = (x - mu) * rs * gl + bl + nf[i];
    }
}

// ---------------------------------------------------------------------------
extern "C" void kernel_launch(void* const* d_in, const int* in_sizes, int n_in,
                              void* d_out, int out_size, void* d_ws, size_t ws_size,
                              hipStream_t stream) {
    const float* efeat = (const float*)d_in[0];
    const float* nfeat = (const float*)d_in[1];
    const int*   dst   = (const int*)  d_in[2];
    const float* W1    = (const float*)d_in[3];
    const float* b1    = (const float*)d_in[4];
    const float* W2    = (const float*)d_in[5];
    const float* b2    = (const float*)d_in[6];
    const float* gamma = (const float*)d_in[7];
    const float* beta  = (const float*)d_in[8];

    float* out_e = (float*)d_out;
    float* out_n = (float*)d_out + (long long)N_EDGES * D;

    int* eidx   = (int*)d_ws;
    int* cnt    = eidx + N_EDGES;
    int* starts = cnt + N_NODES;
    int* cursor = starts + N_NODES;
    int* chunkSum = cursor + N_NODES;
    int* chunkOff = chunkSum + 128;

    zero_cnt <<<(N_NODES + 255) / 256, 256, 0, stream>>>(cnt);
    hist     <<<1024, 256, 0, stream>>>(dst, cnt);
    scan1    <<<NCHUNK, 256, 0, stream>>>(cnt, starts, chunkSum);
    scan2    <<<1, 128, 0, stream>>>(chunkSum, chunkOff);
    scan3    <<<512, 256, 0, stream>>>(starts, chunkOff, cursor);
    bin_edges<<<2048, 256, 0, stream>>>(dst, cursor, eidx);
    fused_mlp<<<(N_NODES + 127) / 128, 512, 0, stream>>>(
        (const float4*)efeat, (float4*)out_e, nfeat,
        starts, cnt, eidx, W1, b1, W2, b2, gamma, beta, out_n);
}

// Round 5
// 1081.966 us; speedup vs baseline: 2.0907x; 1.0171x over previous
//
#include <hip/hip_runtime.h>
#include <hip/hip_bf16.h>
#include <math.h>

#define N_NODES 100000
#define N_EDGES 1600000
#define D 64
#define H 128
#define LN_EPS 1e-5f
#define NCHUNK ((N_NODES + 1023) / 1024)   // 98

// ---------------------------------------------------------------------------
// ws (ints): eidx[E], cnt[N], starts[N+1], cursor[N], chunkSum[128], chunkOff[128]
// ---------------------------------------------------------------------------

__global__ void zero_cnt(int* __restrict__ cnt) {
    int i = blockIdx.x * blockDim.x + threadIdx.x;
    if (i < N_NODES) cnt[i] = 0;
}

__global__ void hist(const int* __restrict__ dst, int* __restrict__ cnt) {
    const int stride = gridDim.x * blockDim.x;
    for (int e = blockIdx.x * blockDim.x + threadIdx.x; e < N_EDGES; e += stride)
        atomicAdd(&cnt[dst[e]], 1);
}

__global__ void scan1(const int* __restrict__ cnt,
                      int* __restrict__ starts,
                      int* __restrict__ chunkSum) {
    __shared__ int ps[256];
    const int t = threadIdx.x;
    const int base = blockIdx.x * 1024 + t * 4;
    int v[4];
    #pragma unroll
    for (int r = 0; r < 4; ++r)
        v[r] = (base + r < N_NODES) ? cnt[base + r] : 0;
    int s = v[0] + v[1] + v[2] + v[3];
    ps[t] = s;
    __syncthreads();
    for (int off = 1; off < 256; off <<= 1) {
        int x = (t >= off) ? ps[t - off] : 0;
        __syncthreads();
        ps[t] += x;
        __syncthreads();
    }
    int run = (t > 0) ? ps[t - 1] : 0;
    #pragma unroll
    for (int r = 0; r < 4; ++r) {
        if (base + r < N_NODES) starts[base + r] = run;
        run += v[r];
    }
    if (t == 255) chunkSum[blockIdx.x] = ps[255];
}

__global__ void scan2(const int* __restrict__ chunkSum,
                      int* __restrict__ chunkOff) {
    __shared__ int ps[128];
    const int t = threadIdx.x;
    int own = (t < NCHUNK) ? chunkSum[t] : 0;
    ps[t] = own;
    __syncthreads();
    for (int off = 1; off < 128; off <<= 1) {
        int x = (t >= off) ? ps[t - off] : 0;
        __syncthreads();
        ps[t] += x;
        __syncthreads();
    }
    chunkOff[t] = ps[t] - own;
}

__global__ void scan3(int* __restrict__ starts,
                      const int* __restrict__ chunkOff,
                      int* __restrict__ cursor) {
    const int gid = blockIdx.x * blockDim.x + threadIdx.x;
    if (gid == 0) starts[N_NODES] = N_EDGES;           // sentinel
    const int stride = gridDim.x * blockDim.x;
    for (int i = gid; i < N_NODES; i += stride) {
        int s = starts[i] + chunkOff[i >> 10];
        starts[i] = s;
        cursor[i] = s;
    }
}

__global__ void bin_edges(const int* __restrict__ dst,
                          int* __restrict__ cursor,
                          int* __restrict__ eidx) {
    const int stride = gridDim.x * blockDim.x;
    for (int e = blockIdx.x * blockDim.x + threadIdx.x; e < N_EDGES; e += stride) {
        int pos = atomicAdd(&cursor[dst[e]], 1);
        eidx[pos] = e;
    }
}

// ---------------------------------------------------------------------------
// Fused: CSR gather-sum (+ efeat pass-through copy) -> concat -> Linear ->
//        SiLU -> Linear -> LayerNorm -> + nfeat
// Block = 512 threads (8 waves), tile = 128 nodes.
// LDS B[128*132] multi-view, node-major with XOR group swizzle:
//   element (n, k) lives at B[n*132 + (((k>>2) ^ (n>>2)) & 31)*4 + (k&3)]
//   O view:        B[n*68  + (((d>>2) ^ (n>>2)) & 15)*4 + (d&3)]
// Swizzle spreads same-k-quad reads across banks (node rows are 16B-aligned,
// so without it 32 node-quads map to 2 banks -> 16-way conflict).
// ---------------------------------------------------------------------------
__device__ __forceinline__ float silu_f(float x) {
    return x / (1.f + __expf(-x));
}

__global__ __launch_bounds__(512, 4)
void fused_mlp(const float4* __restrict__ ef4, float4* __restrict__ out4,
               const float* __restrict__ nfeat,
               const int* __restrict__ starts, const int* __restrict__ eidx,
               const float* __restrict__ W1, const float* __restrict__ b1,
               const float* __restrict__ W2, const float* __restrict__ b2,
               const float* __restrict__ gamma, const float* __restrict__ beta,
               float* __restrict__ out_n) {
    __shared__ float B[128 * 132];   // 67.6 KB -> 2 blocks/CU

    const int tid  = threadIdx.x;
    const int lane = tid & 63;
    const int wave = tid >> 6;          // 0..7
    const int rg   = lane >> 4;         // edge-in-quad 0..3
    const int q    = lane & 15;         // float4 slot within 256B row
    const int nbase = blockIdx.x * 128;

    // ---- Phase 0a: metadata + nfeat preload (independent coalesced loads) --
    int sv = 0;
    {
        const int idx = nbase + wave * 16 + lane;
        if (lane <= 16 && idx <= N_NODES) sv = starts[idx];
    }
    int eidv[16];
    #pragma unroll
    for (int i = 0; i < 16; ++i) {
        const int st = __shfl(sv, i);
        const int dg = __shfl(sv, i + 1) - st;
        eidv[i] = (lane < dg) ? eidx[st + lane] : 0;
        const int col = wave * 16 + i;
        const int n = nbase + col;
        const float nv = (n < N_NODES) ? nfeat[n * D + lane] : 0.f;
        const int g = ((16 + (lane >> 2)) ^ ((col >> 2) & 31)) & 31;
        B[col * 132 + g * 4 + (lane & 3)] = nv;        // k = 64 + lane
    }

    // ---- Phase 0b: gather + pass-through copy ------------------------------
    #pragma unroll
    for (int i = 0; i < 16; ++i) {
        const int col = wave * 16 + i;
        const int st = __shfl(sv, i);
        const int dg = __shfl(sv, i + 1) - st;
        float4 a = make_float4(0.f, 0.f, 0.f, 0.f);
        const int m = dg < 64 ? dg : 64;
        for (int c = 0; c < m; c += 4) {
            const int r = c + rg;
            const int eid = __shfl(eidv[i], r);
            if (r < m) {
                const float4 v = ef4[eid * 16 + q];
                out4[eid * 16 + q] = v;                // copy-through
                a.x += v.x; a.y += v.y; a.z += v.z; a.w += v.w;
            }
        }
        for (int bb = 64; bb < dg; bb += 64) {         // rare deg > 64
            const int rem = dg - bb;
            int e2 = (lane < rem) ? eidx[st + bb + lane] : 0;
            const int m2 = rem < 64 ? rem : 64;
            for (int c = 0; c < m2; c += 4) {
                const int r = c + rg;
                const int eid = __shfl(e2, r);
                if (r < m2) {
                    const float4 v = ef4[eid * 16 + q];
                    out4[eid * 16 + q] = v;
                    a.x += v.x; a.y += v.y; a.z += v.z; a.w += v.w;
                }
            }
        }
        a.x += __shfl_xor(a.x, 16); a.y += __shfl_xor(a.y, 16);
        a.z += __shfl_xor(a.z, 16); a.w += __shfl_xor(a.w, 16);
        a.x += __shfl_xor(a.x, 32); a.y += __shfl_xor(a.y, 32);
        a.z += __shfl_xor(a.z, 32); a.w += __shfl_xor(a.w, 32);
        if (lane < 16) {                                // k-group q (k = 4q..4q+3)
            const int g = (q ^ ((col >> 2) & 31)) & 31;
            *(float4*)&B[col * 132 + g * 4] = a;
        }
    }
    __syncthreads();

    // ---- GEMM1: h = cat @ W1 + b1  (thread tile 4 nodes x 8 hidden) --------
    const int nt = tid & 31;            // node quad: nodes nt*4+i
    const int jg = tid >> 5;            // 0..15, j0 = jg*8
    const int j0 = jg * 8;

    float acc[4][8];
    {
        const float4 bA = *(const float4*)(b1 + j0);
        const float4 bB = *(const float4*)(b1 + j0 + 4);
        #pragma unroll
        for (int i = 0; i < 4; ++i) {
            acc[i][0] = bA.x; acc[i][1] = bA.y; acc[i][2] = bA.z; acc[i][3] = bA.w;
            acc[i][4] = bB.x; acc[i][5] = bB.y; acc[i][6] = bB.z; acc[i][7] = bB.w;
        }
    }
    #pragma unroll 2
    for (int kq = 0; kq < 32; ++kq) {
        const int g = (kq ^ nt) & 31;
        float xv[4][4];
        #pragma unroll
        for (int i = 0; i < 4; ++i) {
            const float4 x4 = *(const float4*)&B[(nt * 4 + i) * 132 + g * 4];
            xv[i][0] = x4.x; xv[i][1] = x4.y; xv[i][2] = x4.z; xv[i][3] = x4.w;
        }
        #pragma unroll
        for (int kk = 0; kk < 4; ++kk) {
            const int k = kq * 4 + kk;
            const float4 wA = *(const float4*)(W1 + k * H + j0);
            const float4 wB = *(const float4*)(W1 + k * H + j0 + 4);
            const float wv[8] = {wA.x, wA.y, wA.z, wA.w, wB.x, wB.y, wB.z, wB.w};
            #pragma unroll
            for (int i = 0; i < 4; ++i)
                #pragma unroll
                for (int j = 0; j < 8; ++j)
                    acc[i][j] = fmaf(xv[i][kk], wv[j], acc[i][j]);
        }
    }
    __syncthreads();

    // ---- SiLU + store s[n][h] (h-groups jg*2, jg*2+1), same swizzle --------
    #pragma unroll
    for (int i = 0; i < 4; ++i) {
        const int n = nt * 4 + i;
        const int g0 = ((jg * 2)     ^ nt) & 31;
        const int g1 = ((jg * 2 + 1) ^ nt) & 31;
        *(float4*)&B[n * 132 + g0 * 4] =
            make_float4(silu_f(acc[i][0]), silu_f(acc[i][1]),
                        silu_f(acc[i][2]), silu_f(acc[i][3]));
        *(float4*)&B[n * 132 + g1 * 4] =
            make_float4(silu_f(acc[i][4]), silu_f(acc[i][5]),
                        silu_f(acc[i][6]), silu_f(acc[i][7]));
    }
    __syncthreads();

    // ---- GEMM2: o = s @ W2 + b2  (thread tile 4 nodes x 4 dims) ------------
    const int dg = tid >> 5;            // 0..15, d0 = dg*4
    const int d0 = dg * 4;
    float o[4][4];
    {
        const float4 b4 = *(const float4*)(b2 + d0);
        #pragma unroll
        for (int i = 0; i < 4; ++i) {
            o[i][0] = b4.x; o[i][1] = b4.y; o[i][2] = b4.z; o[i][3] = b4.w;
        }
    }
    #pragma unroll 2
    for (int hq = 0; hq < 32; ++hq) {
        const int g = (hq ^ nt) & 31;
        float sv4[4][4];
        #pragma unroll
        for (int i = 0; i < 4; ++i) {
            const float4 s4 = *(const float4*)&B[(nt * 4 + i) * 132 + g * 4];
            sv4[i][0] = s4.x; sv4[i][1] = s4.y; sv4[i][2] = s4.z; sv4[i][3] = s4.w;
        }
        #pragma unroll
        for (int hh = 0; hh < 4; ++hh) {
            const int h = hq * 4 + hh;
            const float4 w = *(const float4*)(W2 + h * D + d0);
            const float wv[4] = {w.x, w.y, w.z, w.w};
            #pragma unroll
            for (int i = 0; i < 4; ++i)
                #pragma unroll
                for (int dd = 0; dd < 4; ++dd)
                    o[i][dd] = fmaf(sv4[i][hh], wv[dd], o[i][dd]);
        }
    }
    __syncthreads();

    // ---- store O[n][d] (stride 68, 16 d-groups, swizzled) ------------------
    #pragma unroll
    for (int i = 0; i < 4; ++i) {
        const int n = nt * 4 + i;
        const int g = (dg ^ nt) & 15;
        *(float4*)&B[n * 68 + g * 4] = make_float4(o[i][0], o[i][1], o[i][2], o[i][3]);
    }
    __syncthreads();

    // ---- LayerNorm + residual (nfeat re-read, coalesced) -------------------
    const float gl = gamma[lane];
    const float bl = beta[lane];
    #pragma unroll
    for (int i = 0; i < 16; ++i) {
        const int col = wave * 16 + i;
        const int gn = nbase + col;
        const int g = ((lane >> 2) ^ ((col >> 2) & 15)) & 15;
        float x = B[col * 68 + g * 4 + (lane & 3)];
        float s = x, qq = x * x;
        #pragma unroll
        for (int off = 32; off > 0; off >>= 1) {
            s  += __shfl_xor(s,  off);
            qq += __shfl_xor(qq, off);
        }
        const float mu  = s * (1.f / 64.f);
        const float var = qq * (1.f / 64.f) - mu * mu;
        const float rs  = rsqrtf(var + LN_EPS);
        if (gn < N_NODES) {
            const float nv = nfeat[(long long)gn * D + lane];
            out_n[(long long)gn * D + lane] = (x - mu) * rs * gl + bl + nv;
        }
    }
}

// ---------------------------------------------------------------------------
extern "C" void kernel_launch(void* const* d_in, const int* in_sizes, int n_in,
                              void* d_out, int out_size, void* d_ws, size_t ws_size,
                              hipStream_t stream) {
    const float* efeat = (const float*)d_in[0];
    const float* nfeat = (const float*)d_in[1];
    const int*   dst   = (const int*)  d_in[2];
    const float* W1    = (const float*)d_in[3];
    const float* b1    = (const float*)d_in[4];
    const float* W2    = (const float*)d_in[5];
    const float* b2    = (const float*)d_in[6];
    const float* gamma = (const float*)d_in[7];
    const float* beta  = (const float*)d_in[8];

    float* out_e = (float*)d_out;
    float* out_n = (float*)d_out + (long long)N_EDGES * D;

    int* eidx     = (int*)d_ws;
    int* cnt      = eidx + N_EDGES;
    int* starts   = cnt + N_NODES;          // N+1 entries (sentinel)
    int* cursor   = starts + (N_NODES + 1);
    int* chunkSum = cursor + N_NODES;
    int* chunkOff = chunkSum + 128;

    zero_cnt <<<(N_NODES + 255) / 256, 256, 0, stream>>>(cnt);
    hist     <<<2048, 256, 0, stream>>>(dst, cnt);
    scan1    <<<NCHUNK, 256, 0, stream>>>(cnt, starts, chunkSum);
    scan2    <<<1, 128, 0, stream>>>(chunkSum, chunkOff);
    scan3    <<<512, 256, 0, stream>>>(starts, chunkOff, cursor);
    bin_edges<<<4096, 256, 0, stream>>>(dst, cursor, eidx);
    fused_mlp<<<(N_NODES + 127) / 128, 512, 0, stream>>>(
        (const float4*)efeat, (float4*)out_e, nfeat,
        starts, eidx, W1, b1, W2, b2, gamma, beta, out_n);
}